// Round 2
// baseline (328.645 us; speedup 1.0000x reference)
//
#include <hip/hip_runtime.h>

// Capsule routing, factorized, all fp32. B=256, K_IN=8, C=1152, J=10, D=16, 4 iters.
// m = k*1152 + c  (M_DIM = 9216),  n = j*16 + d  (N_DIM = 160)
// x (B,8,1152) fp32 is flat [b][m]. W (1,1152,10,16,8) fp32 -> Wr[m][n] fp32.
// Per iter: s = Xt^T * (c_ij ⊙ Wr); v = squash(s) -> d_out; b_ij += fold(Wr, Xt*v).

#define B_SZ 256
#define C_IN 1152
#define J_U 10
#define M_DIM 9216
#define N_DIM 160
#define NCHUNK 32    // GEMM1 split-K chunks
#define MCHUNK 288   // M_DIM / NCHUNK

// ---- ws layout (bytes), total 11,233,280 ----
#define OFF_WR     0                      // fp32 [M_DIM][N_DIM]   5,898,240
#define OFF_SPART  5898240                // fp32 [NCHUNK][B][N]   5,242,880
#define OFF_BIJ    11141120               // fp32 [C][J]              46,080
#define OFF_CIJ    11187200               // fp32 [C][J]              46,080

// ---- K0: Wr[(k*C+c)][n] = W[c][n][k]; also zero b_ij. grid 1440x256 ----
__global__ __launch_bounds__(256) void k_build_wr(const float* __restrict__ W,
                                                  float* __restrict__ Wr,
                                                  float* __restrict__ b_ij) {
    const int i = blockIdx.x * 256 + threadIdx.x;     // [0, 368640)
    if (i < C_IN * J_U) b_ij[i] = 0.f;
    const int n  = i % N_DIM;
    const int c  = (i / N_DIM) % C_IN;
    const int kh = i / (N_DIM * C_IN);                // 0..1 (k half)
    const float4 w = *reinterpret_cast<const float4*>(W + (size_t)c * (N_DIM * 8) + n * 8 + kh * 4);
    const float wv[4] = {w.x, w.y, w.z, w.w};
#pragma unroll
    for (int j = 0; j < 4; ++j) {
        const int k = kh * 4 + j;
        Wr[(size_t)(k * C_IN + c) * N_DIM + n] = wv[j];   // lanes vary n -> coalesced
    }
}

// ---- K1: c_ij = softmax_j(b_ij) ----
__global__ __launch_bounds__(256) void k_softmax(const float* __restrict__ b_ij,
                                                 float* __restrict__ c_ij) {
    const int c = blockIdx.x * 256 + threadIdx.x;
    if (c >= C_IN) return;
    float vv[J_U];
    float mx = -1e30f;
#pragma unroll
    for (int j = 0; j < J_U; ++j) { vv[j] = b_ij[c * J_U + j]; mx = fmaxf(mx, vv[j]); }
    float sum = 0.f;
#pragma unroll
    for (int j = 0; j < J_U; ++j) { vv[j] = __expf(vv[j] - mx); sum += vv[j]; }
    const float inv = 1.f / sum;
#pragma unroll
    for (int j = 0; j < J_U; ++j) c_ij[c * J_U + j] = vv[j] * inv;
}

// ---- K2: s_part[ch][b][n] = sum_{m in chunk} x[b][m] * c_ij[c(m)][j(n)] * Wr[m][n]
// grid (NCHUNK, 8). Panels of 72 m (one k-slice each; 1152 % 72 == 0).
__global__ __launch_bounds__(256) void k_gemm1(const float* __restrict__ x,
                                               const float4* __restrict__ Wr4,
                                               const float* __restrict__ c_ij,
                                               float* __restrict__ s_part) {
    __shared__ float Ws[72 * 160];
    __shared__ float Xs[72 * 32];
    const int ch = blockIdx.x;
    const int b0 = blockIdx.y * 32;
    const int t  = threadIdx.x;
    const int bp = t & 15;   // b-pair index
    const int ng = t >> 4;   // n-group: n0 = ng*10
    float acc[2][10] = {};

    for (int sub = 0; sub < 4; ++sub) {
        const int m0 = ch * MCHUNK + sub * 72;
        float4* Ws4 = reinterpret_cast<float4*>(Ws);
        for (int i = t; i < 2880; i += 256) {          // 72 rows x 40 float4
            const int row = i / 40;
            const int q   = i - row * 40;
            const int m   = m0 + row;
            const int c   = m % C_IN;
            const float sc = c_ij[c * J_U + (q >> 2)]; // j = 4q/16, one j per float4
            const float4 w = Wr4[(size_t)m * 40 + q];
            Ws4[i] = make_float4(w.x * sc, w.y * sc, w.z * sc, w.w * sc);
        }
        for (int i = t; i < 576; i += 256) {           // 32 b-rows x 18 float4, LDS transpose
            const int row = i & 31;                    // b (distinct per lane -> no bank conflict)
            const int q   = i >> 5;                    // [0,18)
            const float4 v = *reinterpret_cast<const float4*>(
                x + (size_t)(b0 + row) * M_DIM + m0 + 4 * q);
            Xs[(4 * q + 0) * 32 + row] = v.x;
            Xs[(4 * q + 1) * 32 + row] = v.y;
            Xs[(4 * q + 2) * 32 + row] = v.z;
            Xs[(4 * q + 3) * 32 + row] = v.w;
        }
        __syncthreads();
        const float2* Ws2 = reinterpret_cast<const float2*>(Ws);
        const float2* Xs2 = reinterpret_cast<const float2*>(Xs);
#pragma unroll 4
        for (int m = 0; m < 72; ++m) {
            const float2 xv = Xs2[m * 16 + bp];
#pragma unroll
            for (int jj = 0; jj < 5; ++jj) {
                const float2 wv = Ws2[m * 80 + ng * 5 + jj];
                acc[0][2 * jj]     += xv.x * wv.x;
                acc[0][2 * jj + 1] += xv.x * wv.y;
                acc[1][2 * jj]     += xv.y * wv.x;
                acc[1][2 * jj + 1] += xv.y * wv.y;
            }
        }
        __syncthreads();
    }
#pragma unroll
    for (int bi = 0; bi < 2; ++bi) {
        float2* sp2 = reinterpret_cast<float2*>(
            s_part + (size_t)ch * (B_SZ * N_DIM) + (size_t)(b0 + 2 * bp + bi) * N_DIM + ng * 10);
#pragma unroll
        for (int jj = 0; jj < 5; ++jj)
            sp2[jj] = make_float2(acc[bi][2 * jj], acc[bi][2 * jj + 1]);
    }
}

// ---- K3: reduce split-K partials, squash over d, write v straight to d_out (fp32) ----
__global__ __launch_bounds__(256) void k_squash(const float* __restrict__ s_part,
                                                float* __restrict__ out) {
    __shared__ float sq[N_DIM];
    const int b = blockIdx.x;
    const int t = threadIdx.x;
    float s = 0.f;
    if (t < N_DIM) {
        const float* p = s_part + (size_t)b * N_DIM + t;
#pragma unroll 8
        for (int ch = 0; ch < NCHUNK; ++ch) s += p[(size_t)ch * (B_SZ * N_DIM)];
        s += 1e-5f;                       // reference adds 1e-5 BEFORE magnitudes
        sq[t] = s * s;
    }
    __syncthreads();
    if (t < N_DIM) {
        const int j0 = t & ~15;
        float mag = 0.f;
#pragma unroll
        for (int d = 0; d < 16; ++d) mag += sq[j0 + d];
        out[(size_t)b * N_DIM + t] = s * (sqrtf(mag) / (1.f + mag));
    }
}

// ---- K4: G[m][n] = sum_b x[b][m]*v[b][n] (b-half partial);
//          b_ij[c][j] += sum over this tile of Wr[m][n]*G[m][n]
// grid (144, 2). 64-m tiles never cross a k-slice (1152 % 64 == 0).
__global__ __launch_bounds__(256) void k_gemm2(const float* __restrict__ x,
                                               const float* __restrict__ v,
                                               const float* __restrict__ Wr,
                                               float* __restrict__ b_ij) {
    __shared__ float Xs[64 * 65];   // +1 pad: conflict-free column reads
    __shared__ float Vs[64 * 160];
    __shared__ float agg[640];      // 64 c x 10 j partial agreement
    const int m0 = blockIdx.x * 64;
    const int bh = blockIdx.y * 128;
    const int t  = threadIdx.x;
    const int mq = (t & 15) << 2;   // 4 consecutive m
    const int ng = t >> 4;          // n0 = ng*10
    for (int i = t; i < 640; i += 256) agg[i] = 0.f;
    float acc[4][10] = {};

    for (int sub = 0; sub < 2; ++sub) {
        const int bq = bh + sub * 64;
        float4* Vs4 = reinterpret_cast<float4*>(Vs);
        const float4* v4 = reinterpret_cast<const float4*>(v);
        for (int i = t; i < 2560; i += 256) Vs4[i] = v4[(size_t)bq * 40 + i];
        for (int i = t; i < 1024; i += 256) {          // 64 b-rows x 16 float4, LDS transpose
            const int row = i & 63;                    // b (distinct per lane)
            const int q   = i >> 6;                    // [0,16)
            const float4 xv = *reinterpret_cast<const float4*>(
                x + (size_t)(bq + row) * M_DIM + m0 + 4 * q);
            Xs[(4 * q + 0) * 65 + row] = xv.x;
            Xs[(4 * q + 1) * 65 + row] = xv.y;
            Xs[(4 * q + 2) * 65 + row] = xv.z;
            Xs[(4 * q + 3) * 65 + row] = xv.w;
        }
        __syncthreads();
        const float2* Vs2 = reinterpret_cast<const float2*>(Vs);
#pragma unroll 2
        for (int b = 0; b < 64; ++b) {
            float xv[4];
#pragma unroll
            for (int i = 0; i < 4; ++i) xv[i] = Xs[(mq + i) * 65 + b];
#pragma unroll
            for (int jj = 0; jj < 5; ++jj) {
                const float2 vv = Vs2[b * 80 + ng * 5 + jj];
#pragma unroll
                for (int i = 0; i < 4; ++i) {
                    acc[i][2 * jj]     += xv[i] * vv.x;
                    acc[i][2 * jj + 1] += xv[i] * vv.y;
                }
            }
        }
        __syncthreads();
    }
    // fold with Wr -> per-block agreement in LDS, then global atomics into b_ij
    const int c0 = m0 % C_IN;
#pragma unroll
    for (int i = 0; i < 4; ++i) {
        const int m = m0 + mq + i;
        const float* wrow = Wr + (size_t)m * N_DIM;
        float psum = 0.f;
        int curj = (ng * 10) >> 4;
#pragma unroll
        for (int jj = 0; jj < 10; ++jj) {
            const int n = ng * 10 + jj;
            const int j = n >> 4;
            if (j != curj) {
                atomicAdd(&agg[(mq + i) * J_U + curj], psum);
                psum = 0.f;
                curj = j;
            }
            psum += acc[i][jj] * wrow[n];
        }
        atomicAdd(&agg[(mq + i) * J_U + curj], psum);
    }
    __syncthreads();
    for (int i = t; i < 640; i += 256)
        atomicAdd(&b_ij[(size_t)(c0 + i / J_U) * J_U + (i % J_U)], agg[i]);
}

extern "C" void kernel_launch(void* const* d_in, const int* in_sizes, int n_in,
                              void* d_out, int out_size, void* d_ws, size_t ws_size,
                              hipStream_t stream) {
    const float* x = (const float*)d_in[0];   // (256, 8, 1152) fp32
    const float* W = (const float*)d_in[1];   // (1, 1152, 10, 16, 8) fp32
    float* out = (float*)d_out;               // (256, 10, 16, 1) fp32 — also serves as v
    char* ws = (char*)d_ws;                   // needs ~10.8 MB
    float* Wr     = (float*)(ws + OFF_WR);
    float* s_part = (float*)(ws + OFF_SPART);
    float* b_ij   = (float*)(ws + OFF_BIJ);
    float* c_ij   = (float*)(ws + OFF_CIJ);

    k_build_wr<<<1440, 256, 0, stream>>>(W, Wr, b_ij);

    for (int it = 0; it < 4; ++it) {
        k_softmax<<<5, 256, 0, stream>>>(b_ij, c_ij);
        k_gemm1<<<dim3(NCHUNK, 8), 256, 0, stream>>>(x, (const float4*)Wr, c_ij, s_part);
        k_squash<<<B_SZ, 256, 0, stream>>>(s_part, out);
        if (it < 3)   // last iteration's agreement is never used
            k_gemm2<<<dim3(M_DIM / 64, 2), 256, 0, stream>>>(x, out, Wr, b_ij);
    }
}